// Round 7
// baseline (2803.371 us; speedup 1.0000x reference)
//
#include <hip/hip_runtime.h>
#include <hip/hip_bf16.h>

// ---------------------------------------------------------------------------
// Encoder: emb gather -> LSTM0 -> LSTM1 -> BatchNorm(inference)
// B=64, T=128, D=256, H=1024, 4H=4096, BT=8192 rows.
//
// Round-7 structure:
//  - XW = x@W precomputed by GEMMs; GEMM A operands read from frag-major
//    history buffers.
//  - Recurrence: persistent plain-launch kernels <<<64,256>>> (1 WG/CU via
//    147KB LDS). WG w owns j columns [w*16, w*16+16) (64 pc); 4 waves = 2x2
//    (mt row-half, nt pc-half) 32x32 tiles over FULL K=1024 -> no cross-wave
//    z reduction. U slice LDS-resident; c in registers.
//  - A operand (h) loaded DIRECTLY from global frag-major hall[t] (lane-
//    contiguous 1KB/load), software-pipelined 8-chunk groups, 3 buffers,
//    2 groups ahead (r6 lesson: LDS stage relay cost 8 barriers/step and
//    2.16M bank conflicts; step was 13-barrier latency-bound at 6.5us).
//  - h exchange: per-step slot hall[t+1], agent-scope relaxed atomic stores;
//    readers use normal cached loads (slot lines first-touched after write;
//    kernel-dispatch boundaries invalidate L2 for the GEMM interleave).
//  - Grid barrier: vmcnt(0) + relaxed agent atomicAdd + spin (r2: grid.sync
//    ~30us/step; this is the cheap form, validated r6).
// ---------------------------------------------------------------------------

typedef __attribute__((ext_vector_type(8))) short short8;
typedef __attribute__((ext_vector_type(4))) short short4v;
typedef __attribute__((ext_vector_type(4))) float f32x4;
typedef __attribute__((ext_vector_type(16))) float f32x16;
typedef unsigned short ushort_t;

__device__ __forceinline__ void lgkm0_bar() {
  asm volatile("s_waitcnt lgkmcnt(0)" ::: "memory");
  __builtin_amdgcn_s_barrier();
}

__device__ __forceinline__ ushort_t f2b(float f) {
  __hip_bfloat16 h = __float2bfloat16(f);
  return *reinterpret_cast<ushort_t*>(&h);
}
__device__ __forceinline__ float b2f(ushort_t u) {
  unsigned int x = ((unsigned int)u) << 16;
  return __builtin_bit_cast(float, x);
}
__device__ __forceinline__ float fsigmoid(float x) {
  return 1.f / (1.f + __expf(-x));
}
__device__ __forceinline__ float ftanh(float x) {
  return 1.f - 2.f / (__expf(2.f * x) + 1.f);
}

__device__ __forceinline__ void gload_lds16(const ushort_t* g, ushort_t* l) {
  __builtin_amdgcn_global_load_lds(
      (const __attribute__((address_space(1))) unsigned int*)g,
      (__attribute__((address_space(3))) unsigned int*)l, 16, 0, 0);
}

// frag chunk offset (in ushorts) for row b, k-chunk kcg (8 elems), NKS = K/16
__device__ __forceinline__ size_t chunkoff(int b, int kcg, int NKS) {
  return (size_t)((((b >> 5) * NKS + (kcg >> 1)) << 6) |
                  ((b & 31) | ((kcg & 1) << 5))) * 8;
}

// ---- convert W [K][4096] f32 -> [pc][k] bf16 (GEMM B-operand) -------------
__global__ __launch_bounds__(256) void k_convert(
    const float* __restrict__ src, ushort_t* __restrict__ dst, int kshift) {
  size_t tid = (size_t)blockIdx.x * 256 + threadIdx.x;  // = k*4096 + c
  int k = (int)(tid >> 12);
  int c = (int)(tid & 4095);
  int pc = ((c & 1023) << 2) | (c >> 10);
  dst[((size_t)pc << kshift) + k] = f2b(src[tid]);
}

// ---- convert U [1024][4096] f32 -> per-WG frag slices ---------------------
// slice w (65536 us): ((nt*64 + ks)*64 + l)*8 + e:
//   pc = w*64 + nt*32 + (l&31), k = ks*16 + (l>>5)*8 + e
__global__ __launch_bounds__(256) void k_convert_ucoop(
    const float* __restrict__ src, ushort_t* __restrict__ dst) {
  int cid = blockIdx.x * 256 + threadIdx.x;
  int l = cid & 63;
  int ks = (cid >> 6) & 63;
  int nt = (cid >> 12) & 1;
  int w = cid >> 13;
  int pc = w * 64 + nt * 32 + (l & 31);
  int c = ((pc & 3) << 10) | (pc >> 2);
  int kb = ks * 16 + (l >> 5) * 8;
  short8 v;
#pragma unroll
  for (int e = 0; e < 8; ++e)
    v[e] = (short)f2b(src[(size_t)(kb + e) * 4096 + c]);
  *(short8*)(dst + (size_t)cid * 8) = v;
}

// ---- permute biases -------------------------------------------------------
__global__ __launch_bounds__(256) void k_bias(
    const float* __restrict__ b0, const float* __restrict__ b1,
    float* __restrict__ bp0, float* __restrict__ bp1) {
  int pc = blockIdx.x * 256 + threadIdx.x;
  int c = ((pc & 3) << 10) | (pc >> 2);
  bp0[pc] = b0[c];
  bp1[pc] = b1[c];
}

// ---- embedding gather -> frag-major Xef (32KB per t) ----------------------
__global__ __launch_bounds__(256) void k_gather(
    const int* __restrict__ tokens, const float* __restrict__ emb,
    ushort_t* __restrict__ Xef) {
  int row = blockIdx.x;            // row = t*64 + b
  int t = row >> 6, b = row & 63;
  int tok = tokens[b * 128 + t];
  int d = threadIdx.x;
  Xef[(size_t)t * 16384 + chunkoff(b, d >> 3, 16) + (d & 7)] =
      f2b(emb[(size_t)tok * 256 + d]);
}

// ---- state init: h0 -> hall[0] frag; c0 -> c_st; zero barriers ------------
__global__ __launch_bounds__(256) void k_init(
    const float* __restrict__ h0, const float* __restrict__ c0,
    ushort_t* __restrict__ hall, float* __restrict__ c_st,
    unsigned* __restrict__ bars) {
  int tid = blockIdx.x * 256 + threadIdx.x;
  int b = tid >> 10, jj = tid & 1023;
  c_st[tid] = c0[tid];
  hall[chunkoff(b, jj >> 3, 64) + (jj & 7)] = f2b(h0[tid]);
  if (tid < 2) bars[tid] = 0;
}

// ---- GEMM: C[8192][4096] = A[8192][K] * BT[4096][K]^T ---------------------
// A in frag layout (per-t stride NKS*1024 ushorts). 128x128 tile,
// global_load_lds staging, XCD-blocked mapping (8 wgM inner, wgN outer).
template <int NKS>
__global__ __launch_bounds__(256) void k_gemm(
    const ushort_t* __restrict__ Af, const ushort_t* __restrict__ BT,
    ushort_t* __restrict__ C) {
  const int K = NKS * 16;
  const int xcd = blockIdx.x & 7, loc = blockIdx.x >> 3;
  const int wgM = xcd * 8 + (loc & 7);
  const int wgN = loc >> 3;
  const int tid = threadIdx.x;
  const int l = tid & 63;
  const int wv = tid >> 6;
  const int wvM = wv & 1, wvN = wv >> 1;

  __shared__ __align__(16) ushort_t Alds[4096];
  __shared__ __align__(16) ushort_t Blds[4096];

  const int m0 = wgM * 128, n0 = wgN * 128;
  f32x4 acc[4][4] = {};

  for (int k0 = 0; k0 < K; k0 += 32) {
    __syncthreads();
#pragma unroll
    for (int jj = 0; jj < 2; ++jj) {
      int c = jj * 256 + tid;
      int kc = c >> 7, r = c & 127;
      int R = m0 + r, tt = R >> 6, b = R & 63;
      int kcg = (k0 >> 3) + kc;
      gload_lds16(Af + (size_t)tt * (NKS * 1024) + chunkoff(b, kcg, NKS),
                  (ushort_t*)&Alds[(size_t)(jj * 256 + (tid & ~63)) * 8]);
      gload_lds16(BT + (size_t)(n0 + r) * K + k0 + kc * 8,
                  (ushort_t*)&Blds[(size_t)(jj * 256 + (tid & ~63)) * 8]);
    }
    __syncthreads();

    short8 af[4], bf[4];
#pragma unroll
    for (int mt = 0; mt < 4; ++mt)
      af[mt] = *(const short8*)&Alds[((l >> 4) * 128 + wvM * 64 + mt * 16 + (l & 15)) * 8];
#pragma unroll
    for (int nt = 0; nt < 4; ++nt)
      bf[nt] = *(const short8*)&Blds[((l >> 4) * 128 + wvN * 64 + nt * 16 + (l & 15)) * 8];
#pragma unroll
    for (int mt = 0; mt < 4; ++mt)
#pragma unroll
      for (int nt = 0; nt < 4; ++nt)
        acc[mt][nt] =
            __builtin_amdgcn_mfma_f32_16x16x32_bf16(af[mt], bf[nt], acc[mt][nt], 0, 0, 0);
  }

  const int rr0 = wgM * 128 + wvM * 64 + (l >> 4) * 4;
  const int cc0 = wgN * 128 + wvN * 64 + (l & 15);
#pragma unroll
  for (int mt = 0; mt < 4; ++mt)
#pragma unroll
    for (int nt = 0; nt < 4; ++nt)
#pragma unroll
      for (int r = 0; r < 4; ++r)
        C[(size_t)(rr0 + mt * 16 + r) * 4096 + cc0 + nt * 16] =
            f2b(acc[mt][nt][r]);
}

// ---- persistent LSTM layer (128 steps), plain launch <<<64,256>>> ---------
// WG w: all 64 rows x pc slice w (64 pc = 16 j). Waves: (mt = wv&1 rows,
// nt = wv>>1 pc-half), 32x32x16 MFMA over full K=1024 (64 MFMA/wave/step).
// A fragments loaded directly from global hall[t] (frag-major), pipelined.
template <int LAYER>
__global__ __launch_bounds__(256, 1) void k_pers(
    const ushort_t* __restrict__ Uf,    // frag slices, slice w at w*65536
    const ushort_t* __restrict__ XW,    // [8192][4096] bf16 row-major
    const float* __restrict__ bp,       // [4096] permuted bias
    ushort_t* __restrict__ hall,        // 129 slots x 65536 us (frag)
    float* __restrict__ c_st,           // [64][1024] f32
    float* __restrict__ outp,           // L1: d_out
    const float* __restrict__ gamma, const float* __restrict__ beta,
    const float* __restrict__ mean, const float* __restrict__ var,
    unsigned* __restrict__ bar) {
  const int w = blockIdx.x;             // pc-slice 0..63
  const int tid = threadIdx.x;
  const int l = tid & 63;
  const int wv = tid >> 6;
  const int mt = wv & 1, nt = wv >> 1;

  __shared__ __align__(16) ushort_t Ulds[2][64][512];  // 128KB [nt][ks][l*8]
  __shared__ float zls[4][32][33];                     // 16.9KB per-wave z
  __shared__ ushort_t hbuf[64][16];                    // 2KB h transpose

  // ---- stage U slice (128KB = 8192 chunks) ----
  {
    const ushort_t* src = Uf + (size_t)w * 65536;
    for (int i = tid; i < 8192; i += 256)
      *(short8*)((ushort_t*)Ulds + (size_t)i * 8) =
          *(const short8*)(src + (size_t)i * 8);
  }

  // ---- epilogue constants: thread -> (jl = tid&15, b = bq + q*16) ----
  const int jl = tid & 15, bq = tid >> 4;   // bq 0..15
  const int j = w * 16 + jl;
  float creg[4];
#pragma unroll
  for (int q = 0; q < 4; ++q)
    creg[q] = c_st[(bq + q * 16) * 1024 + j];
  const f32x4 bias_v = *(const f32x4*)(bp + w * 64 + jl * 4);
  float scl = 0.f, sft = 0.f;
  if (LAYER == 1) {
    float inv = rsqrtf(var[j] + 1e-3f);
    scl = inv * gamma[j];
    sft = beta[j] - mean[j] * scl;
  }
  lgkm0_bar();   // Ulds visible

#pragma unroll 1
  for (int t = 0; t < 128; ++t) {
    const ushort_t* hin =
        hall + (size_t)((LAYER == 1 && t == 0) ? 128 : t) * 65536;
    ushort_t* hout = hall + (size_t)(t + 1) * 65536;

    // ---- XW prefetch first (HBM latency, consumed in epilogue) ----
    short4v xw[4];
#pragma unroll
    for (int q = 0; q < 4; ++q)
      xw[q] = *(const short4v*)(
          XW + ((size_t)(t * 64 + bq + q * 16) << 12) + w * 64 + jl * 4);

    // ---- A direct-from-global, 8-chunk groups, 3 buffers, 2 ahead ----
    const ushort_t* Ab = hin + (size_t)mt * 32768 + (size_t)l * 8;
    f32x16 acc[4] = {};
    short8 gA[8], gB[8], gC[8];
    auto pf8 = [&](short8(&dst)[8], int ks) {
#pragma unroll
      for (int i = 0; i < 8; ++i)
        dst[i] = *(const short8*)(Ab + (size_t)(ks + i) * 512);
    };
    auto mma8 = [&](short8(&cur)[8], int ks) {
#pragma unroll
      for (int i = 0; i < 8; ++i) {
        short8 bfr = *(const short8*)&Ulds[nt][ks + i][l * 8];
        acc[i & 3] = __builtin_amdgcn_mfma_f32_32x32x16_bf16(cur[i], bfr,
                                                             acc[i & 3], 0, 0, 0);
      }
    };
    pf8(gA, 0);
    pf8(gB, 8);
    pf8(gC, 16); mma8(gA, 0);
    pf8(gA, 24); mma8(gB, 8);
    pf8(gB, 32); mma8(gC, 16);
    pf8(gC, 40); mma8(gA, 24);
    pf8(gA, 48); mma8(gB, 32);
    pf8(gB, 56); mma8(gC, 40);
    mma8(gA, 48);
    mma8(gB, 56);

    // ---- z to LDS (32x32 C layout: col=l&31, row=(r&3)+8*(r>>2)+4*(l>>5))
    f32x16 zt = acc[0] + acc[1] + acc[2] + acc[3];
#pragma unroll
    for (int r = 0; r < 16; ++r) {
      int row = (r & 3) + 8 * (r >> 2) + 4 * (l >> 5);
      zls[wv][row][l & 31] = zt[r];
    }
    lgkm0_bar();

    // ---- epilogue: gates, c-update, BN ----
#pragma unroll
    for (int q = 0; q < 4; ++q) {
      const int b = bq + q * 16;
      const int wve = (jl >> 3) * 2 + (q >> 1);   // static per q
      const int rowe = bq + (q & 1) * 16;
      const int cb = (jl & 7) * 4;
      f32x4 zv = *(const f32x4*)&zls[wve][rowe][cb];
      float zi = zv[0] + b2f((ushort_t)xw[q][0]) + bias_v[0];
      float zf = zv[1] + b2f((ushort_t)xw[q][1]) + bias_v[1];
      float zg = zv[2] + b2f((ushort_t)xw[q][2]) + bias_v[2];
      float zo = zv[3] + b2f((ushort_t)xw[q][3]) + bias_v[3];
      float ii = fsigmoid(zi), ff = fsigmoid(zf), oo = fsigmoid(zo);
      float gg = ftanh(zg);
      creg[q] = ff * creg[q] + ii * gg;
      float hn = oo * ftanh(creg[q]);
      hbuf[b][jl] = f2b(hn);
      if (LAYER == 1) {
        outp[((size_t)b * 128 + t) * 1024 + j] = hn * scl + sft;
        if (t == 127) {
          outp[8388608 + b * 1024 + j] = hn;
          outp[8454144 + b * 1024 + j] = creg[q];
        }
      } else {
        if (t == 127) c_st[b * 1024 + j] = creg[q];
      }
    }
    lgkm0_bar();   // hbuf ready

    // ---- assemble h chunks; agent-scope stores (cross-XCD visible) ----
    if (tid < 128) {
      const int rb = tid >> 6, l2 = tid & 63;
      const int brow = rb * 32 + (l2 & 31);
      short8 v = *(const short8*)&hbuf[brow][(l2 >> 5) * 8];
      union { short8 s; unsigned u[4]; } cv;
      cv.s = v;
      unsigned* dst = (unsigned*)(hout + (size_t)((rb * 64 + w) * 64 + l2) * 8);
#pragma unroll
      for (int wi = 0; wi < 4; ++wi)
        __hip_atomic_store(dst + wi, cv.u[wi], __ATOMIC_RELAXED,
                           __HIP_MEMORY_SCOPE_AGENT);
    }

    // ---- grid barrier: drain stores, arrive, spin ----
    asm volatile("s_waitcnt vmcnt(0)" ::: "memory");
    __builtin_amdgcn_s_barrier();
    if (tid == 0) {
      __hip_atomic_fetch_add(bar, 1u, __ATOMIC_RELAXED,
                             __HIP_MEMORY_SCOPE_AGENT);
      unsigned tg = 64u * (unsigned)(t + 1);
      while (__hip_atomic_load(bar, __ATOMIC_RELAXED,
                               __HIP_MEMORY_SCOPE_AGENT) < tg)
        __builtin_amdgcn_s_sleep(2);
    }
    __builtin_amdgcn_s_barrier();
  }
}

extern "C" void kernel_launch(void* const* d_in, const int* in_sizes, int n_in,
                              void* d_out, int out_size, void* d_ws,
                              size_t ws_size, hipStream_t stream) {
  const int* tokens = (const int*)d_in[0];
  const float* h0 = (const float*)d_in[1];
  const float* c0 = (const float*)d_in[2];
  const float* emb = (const float*)d_in[3];
  const float* W0 = (const float*)d_in[4];
  const float* U0 = (const float*)d_in[5];
  const float* b0 = (const float*)d_in[6];
  const float* W1 = (const float*)d_in[7];
  const float* U1 = (const float*)d_in[8];
  const float* b1 = (const float*)d_in[9];
  const float* gammap = (const float*)d_in[10];
  const float* betap = (const float*)d_in[11];
  const float* mmean = (const float*)d_in[12];
  const float* mvar = (const float*)d_in[13];

  char* ws = (char*)d_ws;
  ushort_t* Uc0 = (ushort_t*)(ws + 0);             //  8 MB frag U0
  ushort_t* Uc1 = (ushort_t*)(ws + 8388608);       //  8 MB frag U1
  ushort_t* W0f = (ushort_t*)(ws + 16777216);      //  2 MB [pc][256]
  ushort_t* W1f = (ushort_t*)(ws + 18874368);      //  8 MB [pc][1024]
  float* bp0 = (float*)(ws + 27262976);            // 16 KB
  float* bp1 = (float*)(ws + 27279360);            // 16 KB
  ushort_t* Xef = (ushort_t*)(ws + 27295744);      //  4 MB frag emb
  ushort_t* XW = (ushort_t*)(ws + 31490048);       // 64 MB [8192][4096]
  ushort_t* hall = (ushort_t*)(ws + 98598912);     // 16.5 MB: 129 x 128KB
  float* c_st = (float*)(ws + 115507200);          // 256 KB
  unsigned* bars = (unsigned*)(ws + 115769344);    // 8 B

  k_convert_ucoop<<<2048, 256, 0, stream>>>(U0, Uc0);
  k_convert_ucoop<<<2048, 256, 0, stream>>>(U1, Uc1);
  k_convert<<<4096, 256, 0, stream>>>(W0, W0f, 8);
  k_convert<<<16384, 256, 0, stream>>>(W1, W1f, 10);
  k_bias<<<16, 256, 0, stream>>>(b0, b1, bp0, bp1);
  k_gather<<<8192, 256, 0, stream>>>(tokens, emb, Xef);
  k_init<<<256, 256, 0, stream>>>(h0, c0, hall, c_st, bars);

  float* outp = (float*)d_out;

  // ---- layer 0 ----
  k_gemm<16><<<2048, 256, 0, stream>>>(Xef, W0f, XW);
  k_pers<0><<<64, 256, 0, stream>>>(Uc0, XW, bp0, hall, c_st, nullptr,
                                    nullptr, nullptr, nullptr, nullptr,
                                    bars + 0);

  // ---- layer 1 (A of GEMM = hall slots 1..128 = L0 outputs) ----
  k_gemm<64><<<2048, 256, 0, stream>>>(hall + 65536, W1f, XW);
  k_pers<1><<<64, 256, 0, stream>>>(Uc1, XW, bp1, hall, c_st, outp, gammap,
                                    betap, mmean, mvar, bars + 1);
}